// Round 7
// baseline (116.490 us; speedup 1.0000x reference)
//
#include <hip/hip_runtime.h>
#include <math.h>

#define BB 4
#define NN 2048
#define FF 128
#define HH 4
#define DD 32
#define NEG_SLOPE 0.2f
#define LOG2E 1.4426950408889634f

typedef __attribute__((ext_vector_type(8))) short short8;
typedef __attribute__((ext_vector_type(4))) float floatx4;
typedef __attribute__((ext_vector_type(2))) float floatx2;

__device__ __forceinline__ float exp2_fast(float x) {
#if __has_builtin(__builtin_amdgcn_exp2f)
    return __builtin_amdgcn_exp2f(x);
#else
    return exp2f(x);
#endif
}

__device__ __forceinline__ int bit_mask(unsigned int w, int bit) {
#if __has_builtin(__builtin_amdgcn_sbfe)
    return __builtin_amdgcn_sbfe((int)w, bit, 1);    // v_bfe_i32: 0 or -1
#else
    return ((int)(w << (31 - bit))) >> 31;
#endif
}

__device__ __forceinline__ unsigned short to_bf16(float f) {
    unsigned int ui = __float_as_uint(f);
    ui += 0x7FFFu + ((ui >> 16) & 1u);   // RTNE
    return (unsigned short)(ui >> 16);
}

// pack (exp2(e), exp2(0.2e)) as (bf16<<16 | bf16)
__device__ __forceinline__ unsigned int pack_pair(float e) {
    unsigned int p = to_bf16(exp2_fast(e));
    unsigned int n = to_bf16(exp2_fast(NEG_SLOPE * e));
    return (p << 16) | n;
}

// ---------------- K1: prep = {gemm_fused (blocks 0..511), pack_adj (512..1535)}
// gemm: 16 rows/block, 128 thr, 4x4 register tile, ALL-b128 LDS reads.
__global__ __launch_bounds__(128) void k_prep(const float* __restrict__ x,
                                              const float* __restrict__ W,
                                              const float* __restrict__ a_src,
                                              const float* __restrict__ a_dst,
                                              const int* __restrict__ adj,
                                              unsigned short* __restrict__ ht,
                                              float* __restrict__ es_t,
                                              float* __restrict__ ed_t,
                                              unsigned int* __restrict__ bits) {
    __shared__ float xs[16][132];             // 8.4 KB
    __shared__ float wb[128][36];             // 18.4 KB W chunk, natural [o][i]
    __shared__ float as_s[FF], ad_s[FF];
    __shared__ unsigned short tile2[16][136]; // 4.4 KB
    int t = threadIdx.x;

    if (blockIdx.x >= 512) {
        // ---- pack_adj ----
        int idx = (blockIdx.x - 512) * 128 + t;     // 0 .. N*64-1
        int n = idx >> 6, w = idx & 63;
        const int4* base = (const int4*)(adj + (size_t)n * NN + w * 32);
        unsigned int word = 0;
#pragma unroll
        for (int q = 0; q < 8; ++q) {
            int4 a = base[q];
            word |= ((unsigned int)(a.x & 1)) << (q * 4 + 0);
            word |= ((unsigned int)(a.y & 1)) << (q * 4 + 1);
            word |= ((unsigned int)(a.z & 1)) << (q * 4 + 2);
            word |= ((unsigned int)(a.w & 1)) << (q * 4 + 3);
        }
        bits[idx] = word;
        return;
    }

    long rows0 = (long)blockIdx.x * 16;
    as_s[t] = a_src[t]; ad_s[t] = a_dst[t];
#pragma unroll
    for (int k = 0; k < 4; ++k) {             // stage x: 512 float4
        int idx = t + k * 128;
        int r = idx >> 5, f4 = idx & 31;
        float4 v = ((const float4*)(x + (rows0 + r) * FF))[f4];
        *(float4*)&xs[r][f4 * 4] = v;
    }
    int og = t & 31, rg = t >> 5;             // cols og*4..+3, rows rg*4..+3
    float acc[4][4];
#pragma unroll
    for (int a = 0; a < 4; ++a)
#pragma unroll
        for (int c = 0; c < 4; ++c) acc[a][c] = 0.f;

    for (int c4 = 0; c4 < 4; ++c4) {          // K chunks of 32
        __syncthreads();
#pragma unroll
        for (int k = 0; k < 8; ++k) {         // stage W[0..127][c4*32..+31]
            int idx = t + k * 128;
            int wr = idx >> 3, f4 = idx & 7;
            float4 v = *(const float4*)(W + (long)wr * FF + c4 * 32 + f4 * 4);
            *(float4*)&wb[wr][f4 * 4] = v;
        }
        __syncthreads();
#pragma unroll
        for (int ii = 0; ii < 8; ++ii) {      // 4 i at a time, all b128
            int i = ii * 4;
            float4 xv[4], wv[4];
#pragma unroll
            for (int a = 0; a < 4; ++a)
                xv[a] = *(const float4*)&xs[rg * 4 + a][c4 * 32 + i];
#pragma unroll
            for (int c = 0; c < 4; ++c)
                wv[c] = *(const float4*)&wb[og * 4 + c][i];
#pragma unroll
            for (int a = 0; a < 4; ++a)
#pragma unroll
                for (int c = 0; c < 4; ++c) {
                    acc[a][c] += xv[a].x * wv[c].x + xv[a].y * wv[c].y
                               + xv[a].z * wv[c].z + xv[a].w * wv[c].w;
                }
        }
    }

    // epilogue a: edge scores
    int head = og >> 3;
    int b = (int)(rows0 >> 11);
    int m_block = (int)(rows0 & 2047);
    float es[4], ed[4];
#pragma unroll
    for (int a = 0; a < 4; ++a) {
        float s = 0.f, d = 0.f;
#pragma unroll
        for (int c = 0; c < 4; ++c) {
            int col = og * 4 + c;
            s += acc[a][c] * as_s[col];
            d += acc[a][c] * ad_s[col];
        }
        es[a] = s; ed[a] = d;
    }
#pragma unroll
    for (int k = 1; k < 8; k <<= 1) {
#pragma unroll
        for (int a = 0; a < 4; ++a) {
            es[a] += __shfl_xor(es[a], k);
            ed[a] += __shfl_xor(ed[a], k);
        }
    }
    if ((og & 7) == 0) {
        size_t eb = (size_t)(b * HH + head) * NN + m_block + rg * 4;
#pragma unroll
        for (int a = 0; a < 4; ++a) {
            es_t[eb + a] = es[a] * LOG2E;
            ed_t[eb + a] = ed[a] * LOG2E;
        }
    }

    // epilogue b: bf16 transpose -> ht[bh][d][m]
#pragma unroll
    for (int a = 0; a < 4; ++a)
#pragma unroll
        for (int c = 0; c < 4; ++c)
            tile2[rg * 4 + a][og * 4 + c] = to_bf16(acc[a][c]);
    __syncthreads();
    {
        int col = t;                           // 0..127
        int hd = col >> 5, d = col & 31;
        unsigned short* op = ht + ((size_t)(b * HH + hd) * DD + d) * NN + m_block;
#pragma unroll
        for (int h2 = 0; h2 < 2; ++h2) {
            unsigned short tmp[8];
#pragma unroll
            for (int j = 0; j < 8; ++j) tmp[j] = tile2[h2 * 8 + j][col];
            *(int4*)(op + h2 * 8) = *(const int4*)tmp;
        }
    }
}

// ---------------- K2: fused masked-softmax attention + PV via MFMA
// grid (32, 16), 512 thr (8 waves), 2 blocks/CU (74 KB LDS). Per block: 64
// n-rows, one bh. Wave roles: rg2 = wid&3 -> 16-row group, ks = wid>>2
// K-splits each staged m-half into 512-m quarters. Adjacency words needed by
// a wave: {ks*16+[0,16)} U {32+ks*16+[0,16)} -- loaded as two 4-int4 chunks.
#define HBS 1032
__global__ __launch_bounds__(512) void k_attn(
        const unsigned short* __restrict__ ht,
        const unsigned int* __restrict__ bits,
        const float* __restrict__ es_t,
        const float* __restrict__ ed_t,
        float* __restrict__ out) {
    __shared__ unsigned short hb[DD * HBS];   // 66 KB (row pad 8)
    __shared__ unsigned int epk[NN];          // 8 KB packed (Ed_p|Ed_n) bf16 pairs
    int t = threadIdx.x;
    int n0 = blockIdx.x * 64;
    int bh = blockIdx.y;
    int b = bh >> 2, head = bh & 3;

    int wid = t >> 6, lane = t & 63;
    int q = lane >> 4, r = lane & 15;
    int qo = q * 8;
    int ks = wid >> 2, rg2 = wid & 3;
    int n_row = n0 + rg2 * 16 + r;

    // stage packed Ed pairs: 4 m per thread
    {
        float4 v = ((const float4*)(ed_t + (size_t)bh * NN))[t];
        uint4 o = {pack_pair(v.x), pack_pair(v.y), pack_pair(v.z), pack_pair(v.w)};
        ((uint4*)epk)[t] = o;
    }
    // adjacency bits this wave needs: bw[0..3] = words ks*16..+15 (m-half 0),
    // bw[4..7] = words 32+ks*16..+15 (m-half 1)
    int4 bw[8];
    {
        const int4* bp0 = (const int4*)(bits + (size_t)n_row * 64 + ks * 16);
        const int4* bp1 = (const int4*)(bits + (size_t)n_row * 64 + 32 + ks * 16);
#pragma unroll
        for (int g = 0; g < 4; ++g) { bw[g] = bp0[g]; bw[4 + g] = bp1[g]; }
    }
    float esv = es_t[(size_t)bh * NN + n_row];
    floatx2 es2 = {exp2_fast(esv), exp2_fast(NEG_SLOPE * esv)};

    floatx4 acc0 = {0.f, 0.f, 0.f, 0.f};
    floatx4 acc1 = {0.f, 0.f, 0.f, 0.f};
    floatx4 accd = {0.f, 0.f, 0.f, 0.f};
    union { short8 s8; int i[4]; } ones;
    ones.i[0] = 0x3F803F80; ones.i[1] = 0x3F803F80;
    ones.i[2] = 0x3F803F80; ones.i[3] = 0x3F803F80;

    const unsigned short* htp = ht + (size_t)bh * DD * NN;

    for (int half = 0; half < 2; ++half) {
        __syncthreads();                       // hb reuse guard
#pragma unroll
        for (int k = 0; k < 8; ++k) {          // stage m-half of ht: 4096 int4
            int qq = t + k * 512;
            int d = qq >> 7, cm = qq & 127;
            int4 v = *(const int4*)(htp + (size_t)d * NN + half * 1024 + cm * 8);
            *(int4*)&hb[d * HBS + cm * 8] = v;
        }
        __syncthreads();
        const unsigned int* pq = epk + half * 1024 + ks * 512;
        const unsigned short* h0 = &hb[r * HBS + ks * 512 + qo];
        const unsigned short* h1 = &hb[(16 + r) * HBS + ks * 512 + qo];
        int bbase = half * 4;                  // bw int4 index base for this half

#pragma unroll
        for (int it = 0; it < 16; ++it) {      // 16 iters of 32 m
            unsigned int word = (unsigned int)((&bw[bbase + (it >> 2)].x)[it & 3]);
            int mb = it * 32;
            unsigned int wq = word >> qo;
            uint4 u0 = *(const uint4*)(pq + mb + qo);
            uint4 u1 = *(const uint4*)(pq + mb + qo + 4);
            union { short8 s8; int i[4]; } af;
#pragma unroll
            for (int jp = 0; jp < 4; ++jp) {
                unsigned int c0 = (jp < 2) ? (&u0.x)[jp * 2]     : (&u1.x)[(jp - 2) * 2];
                unsigned int c1 = (jp < 2) ? (&u0.x)[jp * 2 + 1] : (&u1.x)[(jp - 2) * 2 + 1];
                floatx2 d0 = {__uint_as_float(c0 & 0xFFFF0000u),
                              __uint_as_float(c0 << 16)};
                floatx2 d1 = {__uint_as_float(c1 & 0xFFFF0000u),
                              __uint_as_float(c1 << 16)};
                floatx2 p0 = es2 * d0;
                floatx2 p1 = es2 * d1;
                float w0 = fmaxf(p0.x, p0.y);
                float w1 = fmaxf(p1.x, p1.y);
                int m0 = bit_mask(wq, 2 * jp);
                int m1 = bit_mask(wq, 2 * jp + 1);
                w0 = __uint_as_float(__float_as_uint(w0) & (unsigned int)m0);
                w1 = __uint_as_float(__float_as_uint(w1) & (unsigned int)m1);
                af.i[jp] = __builtin_amdgcn_perm(__float_as_uint(w1),
                                                 __float_as_uint(w0),
                                                 0x07060302u);
            }
            short8 b0 = *(const short8*)(h0 + mb);
            short8 b1 = *(const short8*)(h1 + mb);
            acc0 = __builtin_amdgcn_mfma_f32_16x16x32_bf16(af.s8, b0, acc0, 0, 0, 0);
            acc1 = __builtin_amdgcn_mfma_f32_16x16x32_bf16(af.s8, b1, acc1, 0, 0, 0);
            accd = __builtin_amdgcn_mfma_f32_16x16x32_bf16(af.s8, ones.s8, accd, 0, 0, 0);
        }
    }

    // K-split pair reduction via LDS (reuse hb)
    __syncthreads();
    float* scr = (float*)hb;
    if (ks == 1) {
        int base = (rg2 * 64 + lane) * 12;
        *(floatx4*)&scr[base + 0] = acc0;
        *(floatx4*)&scr[base + 4] = acc1;
        *(floatx4*)&scr[base + 8] = accd;
    }
    __syncthreads();
    if (ks == 0) {
        int base = (rg2 * 64 + lane) * 12;
        floatx4 p0 = *(const floatx4*)&scr[base + 0];
        floatx4 p1 = *(const floatx4*)&scr[base + 4];
        floatx4 pd = *(const floatx4*)&scr[base + 8];
#pragma unroll
        for (int k = 0; k < 4; ++k) {
            acc0[k] += p0[k]; acc1[k] += p1[k]; accd[k] += pd[k];
        }
        // C/D layout: col = lane&15 (= r = d-index), row = q*4+reg (= n-index)
#pragma unroll
        for (int reg = 0; reg < 4; ++reg) {
            int nrow = n0 + rg2 * 16 + q * 4 + reg;
            float inv = 1.0f / accd[reg];
            float* op = out + ((size_t)(b * NN + nrow)) * FF + head * DD;
            op[r]      = acc0[reg] * inv;
            op[16 + r] = acc1[reg] * inv;
        }
    }
}

extern "C" void kernel_launch(void* const* d_in, const int* in_sizes, int n_in,
                              void* d_out, int out_size, void* d_ws, size_t ws_size,
                              hipStream_t stream) {
    const float* x     = (const float*)d_in[0];
    const int*   adj   = (const int*)d_in[1];
    const float* W     = (const float*)d_in[2];
    const float* a_src = (const float*)d_in[3];
    const float* a_dst = (const float*)d_in[4];
    float* out = (float*)d_out;

    float* es_t = (float*)d_ws;                                // 32,768 f
    float* ed_t = es_t + (size_t)BB * HH * NN;                 // 32,768 f
    unsigned int* bits = (unsigned int*)(ed_t + (size_t)BB * HH * NN);     // 131,072 u32
    unsigned short* ht = (unsigned short*)(bits + (size_t)NN * (NN / 32)); // 2,097,152 bf16

    hipLaunchKernelGGL(k_prep, dim3(1536), dim3(128), 0, stream,
                       x, W, a_src, a_dst, adj, ht, es_t, ed_t, bits);
    hipLaunchKernelGGL(k_attn, dim3(NN / 64, BB * HH), dim3(512), 0, stream,
                       ht, bits, es_t, ed_t, out);
}

// Round 8
// 108.250 us; speedup vs baseline: 1.0761x; 1.0761x over previous
//
#include <hip/hip_runtime.h>
#include <math.h>

#define BB 4
#define NN 2048
#define FF 128
#define HH 4
#define DD 32
#define NEG_SLOPE 0.2f
#define LOG2E 1.4426950408889634f

typedef __attribute__((ext_vector_type(8))) short short8;
typedef __attribute__((ext_vector_type(4))) float floatx4;
typedef __attribute__((ext_vector_type(2))) float floatx2;

__device__ __forceinline__ float exp2_fast(float x) {
#if __has_builtin(__builtin_amdgcn_exp2f)
    return __builtin_amdgcn_exp2f(x);
#else
    return exp2f(x);
#endif
}

__device__ __forceinline__ int bit_mask(unsigned int w, int bit) {
#if __has_builtin(__builtin_amdgcn_sbfe)
    return __builtin_amdgcn_sbfe((int)w, bit, 1);    // v_bfe_i32: 0 or -1
#else
    return ((int)(w << (31 - bit))) >> 31;
#endif
}

__device__ __forceinline__ unsigned short to_bf16(float f) {
    unsigned int ui = __float_as_uint(f);
    ui += 0x7FFFu + ((ui >> 16) & 1u);   // RTNE
    return (unsigned short)(ui >> 16);
}

// ---------------- K1: prep = {gemm_fused (blocks 0..511), pack_adj (512..1535)}
// gemm: 16 rows/block, 128 thr, 4x4 register tile, ALL-b128 LDS reads.
__global__ __launch_bounds__(128) void k_prep(const float* __restrict__ x,
                                              const float* __restrict__ W,
                                              const float* __restrict__ a_src,
                                              const float* __restrict__ a_dst,
                                              const int* __restrict__ adj,
                                              unsigned short* __restrict__ ht,
                                              float* __restrict__ es_t,
                                              float* __restrict__ ed_t,
                                              unsigned int* __restrict__ bits) {
    __shared__ float xs[16][132];             // 8.4 KB
    __shared__ float wb[128][36];             // 18.4 KB W chunk, natural [o][i]
    __shared__ float as_s[FF], ad_s[FF];
    __shared__ unsigned short tile2[16][136]; // 4.4 KB
    int t = threadIdx.x;

    if (blockIdx.x >= 512) {
        // ---- pack_adj ----
        int idx = (blockIdx.x - 512) * 128 + t;     // 0 .. N*64-1
        int n = idx >> 6, w = idx & 63;
        const int4* base = (const int4*)(adj + (size_t)n * NN + w * 32);
        unsigned int word = 0;
#pragma unroll
        for (int q = 0; q < 8; ++q) {
            int4 a = base[q];
            word |= ((unsigned int)(a.x & 1)) << (q * 4 + 0);
            word |= ((unsigned int)(a.y & 1)) << (q * 4 + 1);
            word |= ((unsigned int)(a.z & 1)) << (q * 4 + 2);
            word |= ((unsigned int)(a.w & 1)) << (q * 4 + 3);
        }
        bits[idx] = word;
        return;
    }

    long rows0 = (long)blockIdx.x * 16;
    as_s[t] = a_src[t]; ad_s[t] = a_dst[t];
#pragma unroll
    for (int k = 0; k < 4; ++k) {             // stage x: 512 float4
        int idx = t + k * 128;
        int r = idx >> 5, f4 = idx & 31;
        float4 v = ((const float4*)(x + (rows0 + r) * FF))[f4];
        *(float4*)&xs[r][f4 * 4] = v;
    }
    int og = t & 31, rg = t >> 5;             // cols og*4..+3, rows rg*4..+3
    float acc[4][4];
#pragma unroll
    for (int a = 0; a < 4; ++a)
#pragma unroll
        for (int c = 0; c < 4; ++c) acc[a][c] = 0.f;

    for (int c4 = 0; c4 < 4; ++c4) {          // K chunks of 32
        __syncthreads();
#pragma unroll
        for (int k = 0; k < 8; ++k) {         // stage W[0..127][c4*32..+31]
            int idx = t + k * 128;
            int wr = idx >> 3, f4 = idx & 7;
            float4 v = *(const float4*)(W + (long)wr * FF + c4 * 32 + f4 * 4);
            *(float4*)&wb[wr][f4 * 4] = v;
        }
        __syncthreads();
#pragma unroll
        for (int ii = 0; ii < 8; ++ii) {      // 4 i at a time, all b128
            int i = ii * 4;
            float4 xv[4], wv[4];
#pragma unroll
            for (int a = 0; a < 4; ++a)
                xv[a] = *(const float4*)&xs[rg * 4 + a][c4 * 32 + i];
#pragma unroll
            for (int c = 0; c < 4; ++c)
                wv[c] = *(const float4*)&wb[og * 4 + c][i];
#pragma unroll
            for (int a = 0; a < 4; ++a)
#pragma unroll
                for (int c = 0; c < 4; ++c) {
                    acc[a][c] += xv[a].x * wv[c].x + xv[a].y * wv[c].y
                               + xv[a].z * wv[c].z + xv[a].w * wv[c].w;
                }
        }
    }

    // epilogue a: edge scores
    int head = og >> 3;
    int b = (int)(rows0 >> 11);
    int m_block = (int)(rows0 & 2047);
    float es[4], ed[4];
#pragma unroll
    for (int a = 0; a < 4; ++a) {
        float s = 0.f, d = 0.f;
#pragma unroll
        for (int c = 0; c < 4; ++c) {
            int col = og * 4 + c;
            s += acc[a][c] * as_s[col];
            d += acc[a][c] * ad_s[col];
        }
        es[a] = s; ed[a] = d;
    }
#pragma unroll
    for (int k = 1; k < 8; k <<= 1) {
#pragma unroll
        for (int a = 0; a < 4; ++a) {
            es[a] += __shfl_xor(es[a], k);
            ed[a] += __shfl_xor(ed[a], k);
        }
    }
    if ((og & 7) == 0) {
        size_t eb = (size_t)(b * HH + head) * NN + m_block + rg * 4;
#pragma unroll
        for (int a = 0; a < 4; ++a) {
            es_t[eb + a] = es[a] * LOG2E;
            ed_t[eb + a] = ed[a] * LOG2E;
        }
    }

    // epilogue b: bf16 transpose -> ht[bh][d][m]
#pragma unroll
    for (int a = 0; a < 4; ++a)
#pragma unroll
        for (int c = 0; c < 4; ++c)
            tile2[rg * 4 + a][og * 4 + c] = to_bf16(acc[a][c]);
    __syncthreads();
    {
        int col = t;                           // 0..127
        int hd = col >> 5, d = col & 31;
        unsigned short* op = ht + ((size_t)(b * HH + hd) * DD + d) * NN + m_block;
#pragma unroll
        for (int h2 = 0; h2 < 2; ++h2) {
            unsigned short tmp[8];
#pragma unroll
            for (int j = 0; j < 8; ++j) tmp[j] = tile2[h2 * 8 + j][col];
            *(int4*)(op + h2 * 8) = *(const int4*)tmp;
        }
    }
}

// ---------------- K2: fused masked-softmax attention + PV via MFMA
// R5 version VERBATIM (bisect: only k_prep changed this round).
// grid (16,16), 1024 thr (16 waves, K-split halves), 1 block/CU, 144.5KB LDS.
#define HTS 2056
__global__ __launch_bounds__(1024) void k_attn(
        const unsigned short* __restrict__ ht,
        const unsigned int* __restrict__ bits,
        const float* __restrict__ es_t,
        const float* __restrict__ ed_t,
        float* __restrict__ out) {
    __shared__ unsigned short hb[DD * HTS];   // 128.5 KB
    __shared__ float ep[NN * 2];               // 16 KB: (Ed_p, Ed_n) per m
    int t = threadIdx.x;
    int n0 = blockIdx.x * 128;
    int bh = blockIdx.y;
    int b = bh >> 2, head = bh & 3;

    int wid = t >> 6, lane = t & 63;
    int q = lane >> 4, r = lane & 15;
    int qo = q * 8;
    int half = wid >> 3, wsub = wid & 7;
    int n_l = wsub * 16 + r;

    // stage (Ed_p, Ed_n) pairs: 2 m per thread
    {
        float2 v = ((const float2*)(ed_t + (size_t)bh * NN))[t];
        float4 o;
        o.x = exp2_fast(v.x); o.y = exp2_fast(NEG_SLOPE * v.x);
        o.z = exp2_fast(v.y); o.w = exp2_fast(NEG_SLOPE * v.y);
        ((float4*)ep)[t] = o;
    }
    // stage full ht slice: 8192 int4 chunks
    {
        const unsigned short* htp = ht + (size_t)bh * DD * NN;
#pragma unroll
        for (int k = 0; k < 8; ++k) {
            int qq = t + k * 1024;
            int d = qq >> 8, cm = qq & 255;
            int4 v = *(const int4*)(htp + (size_t)d * NN + cm * 8);
            *(int4*)&hb[d * HTS + cm * 8] = v;
        }
    }
    // adjacency bits for this lane's row + K-half: 32 words in registers
    int4 bw[8];
    {
        const int4* bp = (const int4*)(bits + (size_t)(n0 + n_l) * 64 + half * 32);
#pragma unroll
        for (int g = 0; g < 8; ++g) bw[g] = bp[g];
    }
    float esv = es_t[(size_t)bh * NN + n0 + n_l];
    floatx2 es2 = {exp2_fast(esv), exp2_fast(NEG_SLOPE * esv)};
    __syncthreads();

    floatx4 acc0 = {0.f, 0.f, 0.f, 0.f};
    floatx4 acc1 = {0.f, 0.f, 0.f, 0.f};
    floatx4 accd = {0.f, 0.f, 0.f, 0.f};
    union { short8 s8; int i[4]; } ones;
    ones.i[0] = 0x3F803F80; ones.i[1] = 0x3F803F80;
    ones.i[2] = 0x3F803F80; ones.i[3] = 0x3F803F80;

    const float* eph = ep + half * 2048;                       // pairs, this half
    const unsigned short* hrow0 = &hb[r * HTS + half * 1024 + qo];
    const unsigned short* hrow1 = hrow0 + 16 * HTS;

#pragma unroll
    for (int g = 0; g < 8; ++g) {
#pragma unroll
        for (int c = 0; c < 4; ++c) {
            unsigned int word = (unsigned int)((&bw[g].x)[c]);
            int mb = (g * 4 + c) * 32;
            unsigned int wq = word >> qo;
            const float* pbase = eph + (mb + qo) * 2;
            union { short8 s8; int i[4]; } af;
#pragma unroll
            for (int jp = 0; jp < 4; ++jp) {
                float4 d2 = *(const float4*)(pbase + jp * 4);  // Edp0,Edn0,Edp1,Edn1
                floatx2 p0 = es2 * (floatx2){d2.x, d2.y};      // v_pk_mul_f32
                floatx2 p1 = es2 * (floatx2){d2.z, d2.w};
                float w0 = fmaxf(p0.x, p0.y);
                float w1 = fmaxf(p1.x, p1.y);
                int m0 = bit_mask(wq, 2 * jp);
                int m1 = bit_mask(wq, 2 * jp + 1);
                w0 = __uint_as_float(__float_as_uint(w0) & (unsigned int)m0);
                w1 = __uint_as_float(__float_as_uint(w1) & (unsigned int)m1);
                af.i[jp] = __builtin_amdgcn_perm(__float_as_uint(w1),
                                                 __float_as_uint(w0),
                                                 0x07060302u);
            }
            short8 b0 = *(const short8*)(hrow0 + mb);
            short8 b1 = *(const short8*)(hrow1 + mb);
            acc0 = __builtin_amdgcn_mfma_f32_16x16x32_bf16(af.s8, b0, acc0, 0, 0, 0);
            acc1 = __builtin_amdgcn_mfma_f32_16x16x32_bf16(af.s8, b1, acc1, 0, 0, 0);
            accd = __builtin_amdgcn_mfma_f32_16x16x32_bf16(af.s8, ones.s8, accd, 0, 0, 0);
        }
    }

    // K-half pair reduction through LDS (reuse hb as fp32 scratch, 24KB)
    __syncthreads();
    float* scr = (float*)hb;
    if (wid >= 8) {
        int base = ((wid - 8) * 64 + lane) * 12;
        *(floatx4*)&scr[base + 0] = acc0;
        *(floatx4*)&scr[base + 4] = acc1;
        *(floatx4*)&scr[base + 8] = accd;
    }
    __syncthreads();
    if (wid < 8) {
        int base = (wid * 64 + lane) * 12;
        floatx4 p0 = *(const floatx4*)&scr[base + 0];
        floatx4 p1 = *(const floatx4*)&scr[base + 4];
        floatx4 pd = *(const floatx4*)&scr[base + 8];
#pragma unroll
        for (int k = 0; k < 4; ++k) {
            acc0[k] += p0[k]; acc1[k] += p1[k]; accd[k] += pd[k];
        }
        // C/D layout: col = lane&15 (= r), row = q*4 + reg
#pragma unroll
        for (int reg = 0; reg < 4; ++reg) {
            int nrow = n0 + wsub * 16 + q * 4 + reg;
            float inv = 1.0f / accd[reg];
            float* op = out + ((size_t)(b * NN + nrow)) * FF + head * DD;
            op[r]      = acc0[reg] * inv;
            op[16 + r] = acc1[reg] * inv;
        }
    }
}

extern "C" void kernel_launch(void* const* d_in, const int* in_sizes, int n_in,
                              void* d_out, int out_size, void* d_ws, size_t ws_size,
                              hipStream_t stream) {
    const float* x     = (const float*)d_in[0];
    const int*   adj   = (const int*)d_in[1];
    const float* W     = (const float*)d_in[2];
    const float* a_src = (const float*)d_in[3];
    const float* a_dst = (const float*)d_in[4];
    float* out = (float*)d_out;

    float* es_t = (float*)d_ws;                                // 32,768 f
    float* ed_t = es_t + (size_t)BB * HH * NN;                 // 32,768 f
    unsigned int* bits = (unsigned int*)(ed_t + (size_t)BB * HH * NN);     // 131,072 u32
    unsigned short* ht = (unsigned short*)(bits + (size_t)NN * (NN / 32)); // 2,097,152 bf16

    hipLaunchKernelGGL(k_prep, dim3(1536), dim3(128), 0, stream,
                       x, W, a_src, a_dst, adj, ht, es_t, ed_t, bits);
    hipLaunchKernelGGL(k_attn, dim3(NN / 128, BB * HH), dim3(1024), 0, stream,
                       ht, bits, es_t, ed_t, out);
}

// Round 9
// 105.808 us; speedup vs baseline: 1.1009x; 1.0231x over previous
//
#include <hip/hip_runtime.h>
#include <math.h>

#define BB 4
#define NN 2048
#define FF 128
#define HH 4
#define DD 32
#define NEG_SLOPE 0.2f
#define LOG2E 1.4426950408889634f

typedef __attribute__((ext_vector_type(8))) short short8;
typedef __attribute__((ext_vector_type(16))) float floatx16;
typedef __attribute__((ext_vector_type(4))) float floatx4;
typedef __attribute__((ext_vector_type(2))) float floatx2;

__device__ __forceinline__ float exp2_fast(float x) {
#if __has_builtin(__builtin_amdgcn_exp2f)
    return __builtin_amdgcn_exp2f(x);
#else
    return exp2f(x);
#endif
}

__device__ __forceinline__ int bit_mask(unsigned int w, int bit) {
#if __has_builtin(__builtin_amdgcn_sbfe)
    return __builtin_amdgcn_sbfe((int)w, bit, 1);    // v_bfe_i32: 0 or -1
#else
    return ((int)(w << (31 - bit))) >> 31;
#endif
}

__device__ __forceinline__ unsigned short to_bf16(float f) {
    unsigned int ui = __float_as_uint(f);
    ui += 0x7FFFu + ((ui >> 16) & 1u);   // RTNE
    return (unsigned short)(ui >> 16);
}

// ---------------- K1: prep (R5 verbatim) = {gemm_fused blocks 0..511, pack_adj 512..1023}
__global__ __launch_bounds__(256) void k_prep(const float* __restrict__ x,
                                              const float* __restrict__ W,
                                              const float* __restrict__ a_src,
                                              const float* __restrict__ a_dst,
                                              const int* __restrict__ adj,
                                              unsigned short* __restrict__ ht,
                                              float* __restrict__ es_t,
                                              float* __restrict__ ed_t,
                                              unsigned int* __restrict__ bits) {
    __shared__ float xs[16][FF];
    __shared__ float wt[32][132];
    __shared__ float as_s[FF], ad_s[FF];
    __shared__ unsigned short tile2[16][136];
    int t = threadIdx.x;

    if (blockIdx.x >= 512) {
        int idx = (blockIdx.x - 512) * 256 + t;
        int n = idx >> 6, w = idx & 63;
        const int4* base = (const int4*)(adj + (size_t)n * NN + w * 32);
        unsigned int word = 0;
#pragma unroll
        for (int q = 0; q < 8; ++q) {
            int4 a = base[q];
            word |= ((unsigned int)(a.x & 1)) << (q * 4 + 0);
            word |= ((unsigned int)(a.y & 1)) << (q * 4 + 1);
            word |= ((unsigned int)(a.z & 1)) << (q * 4 + 2);
            word |= ((unsigned int)(a.w & 1)) << (q * 4 + 3);
        }
        bits[idx] = word;
        return;
    }

    long rows0 = (long)blockIdx.x * 16;
    if (t < FF) { as_s[t] = a_src[t]; ad_s[t] = a_dst[t]; }
#pragma unroll
    for (int k = 0; k < 2; ++k) {
        int q = t + k * 256;
        int r = q >> 5, c4 = q & 31;
        float4 v = ((const float4*)(x + (rows0 + r) * FF))[c4];
        *(float4*)&xs[r][c4 * 4] = v;
    }
    int og = t & 31, rg = t >> 5;
    float acc[2][4];
#pragma unroll
    for (int a = 0; a < 2; ++a)
#pragma unroll
        for (int c = 0; c < 4; ++c) acc[a][c] = 0.f;

    int wo = t & 127, wg = t >> 7;
    for (int i0 = 0; i0 < FF; i0 += 32) {
        __syncthreads();
#pragma unroll
        for (int u = 0; u < 4; ++u) {
            float4 v = *(const float4*)(W + (long)wo * FF + i0 + wg * 16 + u * 4);
            wt[wg * 16 + u * 4 + 0][wo] = v.x;
            wt[wg * 16 + u * 4 + 1][wo] = v.y;
            wt[wg * 16 + u * 4 + 2][wo] = v.z;
            wt[wg * 16 + u * 4 + 3][wo] = v.w;
        }
        __syncthreads();
#pragma unroll
        for (int i = 0; i < 32; ++i) {
            float4 w4 = *(const float4*)&wt[i][og * 4];
            float x0 = xs[rg * 2 + 0][i0 + i];
            float x1 = xs[rg * 2 + 1][i0 + i];
            acc[0][0] += x0 * w4.x; acc[0][1] += x0 * w4.y;
            acc[0][2] += x0 * w4.z; acc[0][3] += x0 * w4.w;
            acc[1][0] += x1 * w4.x; acc[1][1] += x1 * w4.y;
            acc[1][2] += x1 * w4.z; acc[1][3] += x1 * w4.w;
        }
    }

    int head = og >> 3;
    int b = (int)(rows0 >> 11);
    int m_block = (int)(rows0 & 2047);
    float es0 = 0.f, ed0 = 0.f, es1 = 0.f, ed1 = 0.f;
#pragma unroll
    for (int c = 0; c < 4; ++c) {
        int col = og * 4 + c;
        es0 += acc[0][c] * as_s[col]; ed0 += acc[0][c] * ad_s[col];
        es1 += acc[1][c] * as_s[col]; ed1 += acc[1][c] * ad_s[col];
    }
#pragma unroll
    for (int k = 1; k < 8; k <<= 1) {
        es0 += __shfl_xor(es0, k); ed0 += __shfl_xor(ed0, k);
        es1 += __shfl_xor(es1, k); ed1 += __shfl_xor(ed1, k);
    }
    if ((og & 7) == 0) {
        size_t eb = (size_t)(b * HH + head) * NN + m_block + rg * 2;
        es_t[eb]     = es0 * LOG2E; ed_t[eb]     = ed0 * LOG2E;
        es_t[eb + 1] = es1 * LOG2E; ed_t[eb + 1] = ed1 * LOG2E;
    }

#pragma unroll
    for (int a = 0; a < 2; ++a)
#pragma unroll
        for (int c = 0; c < 4; ++c)
            tile2[rg * 2 + a][og * 4 + c] = to_bf16(acc[a][c]);
    __syncthreads();
    {
        int cg = t >> 1, half = t & 1;
        int d = cg & 31, hd = cg >> 5;
        unsigned short tmp[8];
#pragma unroll
        for (int j = 0; j < 8; ++j) tmp[j] = tile2[half * 8 + j][cg];
        unsigned short* op = ht + ((size_t)(b * HH + hd) * DD + d) * NN + m_block + half * 8;
        *(int4*)op = *(const int4*)tmp;
    }
}

// ---------------- K2: attention via mfma_f32_32x32x16_bf16
// grid (16,16), 1024 thr, 1 blk/CU, 144.5KB LDS. Per iter (32n x 32d x 16m):
// 2 b128 ep reads + 1 b128 hb read + 2 MFMA (num + ones-denominator).
// Wave roles: ng = wid&3 (32-row n-group), ks = wid>>2 (512-m K-quarter).
// Lane: n = lane&31 (A row), oct = lane>>5 (k-octet, 8 consecutive m).
#define HTS 2056
__global__ __launch_bounds__(1024) void k_attn(
        const unsigned short* __restrict__ ht,
        const unsigned int* __restrict__ bits,
        const float* __restrict__ es_t,
        const float* __restrict__ ed_t,
        float* __restrict__ out) {
    __shared__ unsigned short hb[DD * HTS];   // 128.5 KB, [d][m]
    __shared__ float ep[NN * 2];               // 16 KB (Ed_p, Ed_n) per m
    int t = threadIdx.x;
    int n0 = blockIdx.x * 128;
    int bh = blockIdx.y;
    int b = bh >> 2, head = bh & 3;

    int wid = t >> 6, lane = t & 63;
    int nl = lane & 31;          // A row / B col / out d
    int oct = lane >> 5;         // k-octet select
    int ng = wid & 3, ks = wid >> 2;
    int n_row = n0 + ng * 32 + nl;

    // stage (Ed_p, Ed_n) pairs: 2 m per thread
    {
        float2 v = ((const float2*)(ed_t + (size_t)bh * NN))[t];
        float4 o;
        o.x = exp2_fast(v.x); o.y = exp2_fast(NEG_SLOPE * v.x);
        o.z = exp2_fast(v.y); o.w = exp2_fast(NEG_SLOPE * v.y);
        ((float4*)ep)[t] = o;
    }
    // stage full ht slice: 8192 int4 chunks
    {
        const unsigned short* htp = ht + (size_t)bh * DD * NN;
#pragma unroll
        for (int k = 0; k < 8; ++k) {
            int qq = t + k * 1024;
            int d = qq >> 8, cm = qq & 255;
            int4 v = *(const int4*)(htp + (size_t)d * NN + cm * 8);
            *(int4*)&hb[d * HTS + cm * 8] = v;
        }
    }
    // adjacency: 16 words (this row, this 512-m quarter) in 4 int4 regs
    int4 bw[4];
    {
        const int4* bp = (const int4*)(bits + (size_t)n_row * 64 + ks * 16);
#pragma unroll
        for (int g = 0; g < 4; ++g) bw[g] = bp[g];
    }
    float esv = es_t[(size_t)bh * NN + n_row];
    floatx2 es2 = {exp2_fast(esv), exp2_fast(NEG_SLOPE * esv)};
    __syncthreads();

    floatx16 acc, accd;
#pragma unroll
    for (int k = 0; k < 16; ++k) { acc[k] = 0.f; accd[k] = 0.f; }
    union { short8 s8; int i[4]; } ones;
    ones.i[0] = 0x3F803F80; ones.i[1] = 0x3F803F80;
    ones.i[2] = 0x3F803F80; ones.i[3] = 0x3F803F80;

    const float* pq = ep + (size_t)(ks * 512 + oct * 8) * 2;   // pair base, it=0
    const unsigned short* hrow = &hb[(size_t)nl * HTS + ks * 512 + oct * 8];
    int shift = oct * 8;

#pragma unroll
    for (int it = 0; it < 32; ++it) {          // 16 m per iter
        unsigned int word = (unsigned int)((&bw[it >> 3].x)[(it >> 1) & 3]);
        unsigned int wq = word >> (((it & 1) << 4) + shift);
        const float* pb = pq + it * 32;
        union { short8 s8; int i[4]; } af;
#pragma unroll
        for (int jp = 0; jp < 4; ++jp) {
            float4 d2 = *(const float4*)(pb + jp * 4);   // Edp0,Edn0,Edp1,Edn1
            floatx2 p0 = es2 * (floatx2){d2.x, d2.y};
            floatx2 p1 = es2 * (floatx2){d2.z, d2.w};
            float w0 = fmaxf(p0.x, p0.y);
            float w1 = fmaxf(p1.x, p1.y);
            int m0 = bit_mask(wq, 2 * jp);
            int m1 = bit_mask(wq, 2 * jp + 1);
            w0 = __uint_as_float(__float_as_uint(w0) & (unsigned int)m0);
            w1 = __uint_as_float(__float_as_uint(w1) & (unsigned int)m1);
            af.i[jp] = __builtin_amdgcn_perm(__float_as_uint(w1),
                                             __float_as_uint(w0),
                                             0x07060302u);
        }
        short8 bf = *(const short8*)(hrow + it * 16);
        acc  = __builtin_amdgcn_mfma_f32_32x32x16_bf16(af.s8, bf, acc, 0, 0, 0);
        accd = __builtin_amdgcn_mfma_f32_32x32x16_bf16(af.s8, ones.s8, accd, 0, 0, 0);
    }

    // K-quarter reduction through LDS (reuse hb as fp32 scratch, 96KB)
    __syncthreads();
    float* scr = (float*)hb;
    if (ks > 0) {
        int base = ((((ks - 1) * 4 + ng) * 64) + lane) * 32;
#pragma unroll
        for (int k2 = 0; k2 < 4; ++k2) {
            float4 v0 = {acc[k2 * 4], acc[k2 * 4 + 1], acc[k2 * 4 + 2], acc[k2 * 4 + 3]};
            float4 v1 = {accd[k2 * 4], accd[k2 * 4 + 1], accd[k2 * 4 + 2], accd[k2 * 4 + 3]};
            *(float4*)&scr[base + k2 * 4] = v0;
            *(float4*)&scr[base + 16 + k2 * 4] = v1;
        }
    }
    __syncthreads();
    if (ks == 0) {
#pragma unroll
        for (int s = 0; s < 3; ++s) {
            int base = (((s * 4 + ng) * 64) + lane) * 32;
#pragma unroll
            for (int k2 = 0; k2 < 4; ++k2) {
                float4 v0 = *(const float4*)&scr[base + k2 * 4];
                float4 v1 = *(const float4*)&scr[base + 16 + k2 * 4];
                acc[k2 * 4 + 0] += v0.x; acc[k2 * 4 + 1] += v0.y;
                acc[k2 * 4 + 2] += v0.z; acc[k2 * 4 + 3] += v0.w;
                accd[k2 * 4 + 0] += v1.x; accd[k2 * 4 + 1] += v1.y;
                accd[k2 * 4 + 2] += v1.z; accd[k2 * 4 + 3] += v1.w;
            }
        }
        // C/D layout (m74/m101-verified): col = lane&31, row = (reg&3)+8*(reg>>2)+4*oct
#pragma unroll
        for (int reg = 0; reg < 16; ++reg) {
            int nrow = n0 + ng * 32 + (reg & 3) + 8 * (reg >> 2) + 4 * oct;
            float inv = 1.0f / accd[reg];
            out[((size_t)(b * NN + nrow)) * FF + head * DD + nl] = acc[reg] * inv;
        }
    }
}

extern "C" void kernel_launch(void* const* d_in, const int* in_sizes, int n_in,
                              void* d_out, int out_size, void* d_ws, size_t ws_size,
                              hipStream_t stream) {
    const float* x     = (const float*)d_in[0];
    const int*   adj   = (const int*)d_in[1];
    const float* W     = (const float*)d_in[2];
    const float* a_src = (const float*)d_in[3];
    const float* a_dst = (const float*)d_in[4];
    float* out = (float*)d_out;

    float* es_t = (float*)d_ws;                                // 32,768 f
    float* ed_t = es_t + (size_t)BB * HH * NN;                 // 32,768 f
    unsigned int* bits = (unsigned int*)(ed_t + (size_t)BB * HH * NN);     // 131,072 u32
    unsigned short* ht = (unsigned short*)(bits + (size_t)NN * (NN / 32)); // 2,097,152 bf16

    hipLaunchKernelGGL(k_prep, dim3(1024), dim3(256), 0, stream,
                       x, W, a_src, a_dst, adj, ht, es_t, ed_t, bits);
    hipLaunchKernelGGL(k_attn, dim3(NN / 128, BB * HH), dim3(1024), 0, stream,
                       ht, bits, es_t, ed_t, out);
}

// Round 10
// 101.834 us; speedup vs baseline: 1.1439x; 1.0390x over previous
//
#include <hip/hip_runtime.h>
#include <math.h>

#define BB 4
#define NN 2048
#define FF 128
#define HH 4
#define DD 32
#define NEG_SLOPE 0.2f
#define LOG2E 1.4426950408889634f

typedef __attribute__((ext_vector_type(8))) short short8;
typedef __attribute__((ext_vector_type(4))) float floatx4;
typedef __attribute__((ext_vector_type(2))) float floatx2;

__device__ __forceinline__ float exp2_fast(float x) {
#if __has_builtin(__builtin_amdgcn_exp2f)
    return __builtin_amdgcn_exp2f(x);
#else
    return exp2f(x);
#endif
}

__device__ __forceinline__ int bit_mask(unsigned int w, int bit) {
#if __has_builtin(__builtin_amdgcn_sbfe)
    return __builtin_amdgcn_sbfe((int)w, bit, 1);    // v_bfe_i32: 0 or -1
#else
    return ((int)(w << (31 - bit))) >> 31;
#endif
}

__device__ __forceinline__ unsigned short to_bf16(float f) {
    unsigned int ui = __float_as_uint(f);
    ui += 0x7FFFu + ((ui >> 16) & 1u);   // RTNE
    return (unsigned short)(ui >> 16);
}

// pack two fp32 -> one u32 holding (bf16(hi)<<16 | bf16(lo)), RTNE
__device__ __forceinline__ unsigned int pack2_rtne(float lo, float hi) {
    unsigned int ul = __float_as_uint(lo); ul += 0x7FFFu + ((ul >> 16) & 1u);
    unsigned int uh = __float_as_uint(hi); uh += 0x7FFFu + ((uh >> 16) & 1u);
    return (ul >> 16) | (uh & 0xFFFF0000u);
}

// ---------------- K1: prep = {MFMA gemm_fused (blocks 0..511), pack_adj (512..1023)}
// gemm: 16 rows x 128 cols per block via mfma_f32_16x16x32_bf16 (verified
// fragment layouts). es/ed computed in FULL fp32 via v = W^T a  (decoupled
// from the bf16 h path): es[head][m] = x[m] . vs[head].
__global__ __launch_bounds__(256) void k_prep(const float* __restrict__ x,
                                              const float* __restrict__ W,
                                              const float* __restrict__ a_src,
                                              const float* __restrict__ a_dst,
                                              const int* __restrict__ adj,
                                              unsigned short* __restrict__ ht,
                                              float* __restrict__ es_t,
                                              float* __restrict__ ed_t,
                                              unsigned int* __restrict__ bits) {
    __shared__ unsigned short wbf[128][144];   // 36.9 KB, W as bf16 [o][i]
    __shared__ unsigned short hbf[128][24];    // 6 KB, h^T as bf16 [o][m_local]
    __shared__ float vs_s[HH][FF], vd_s[HH][FF];   // 4 KB
    __shared__ float as_s[FF], ad_s[FF];           // 1 KB
    int t = threadIdx.x;

    if (blockIdx.x >= 512) {
        // ---- pack_adj (R5 verbatim) ----
        int idx = (blockIdx.x - 512) * 256 + t;
        int n = idx >> 6, w = idx & 63;
        const int4* base = (const int4*)(adj + (size_t)n * NN + w * 32);
        unsigned int word = 0;
#pragma unroll
        for (int q = 0; q < 8; ++q) {
            int4 a = base[q];
            word |= ((unsigned int)(a.x & 1)) << (q * 4 + 0);
            word |= ((unsigned int)(a.y & 1)) << (q * 4 + 1);
            word |= ((unsigned int)(a.z & 1)) << (q * 4 + 2);
            word |= ((unsigned int)(a.w & 1)) << (q * 4 + 3);
        }
        bits[idx] = word;
        return;
    }

    int m0g = blockIdx.x * 16;
    int b = m0g >> 11;
    int m_block = m0g & 2047;

    if (t < FF) { as_s[t] = a_src[t]; ad_s[t] = a_dst[t]; }
    // stage W -> bf16 LDS: 2048 chunks of 8 shorts
#pragma unroll
    for (int k = 0; k < 8; ++k) {
        int idx = t + k * 256;
        int row = idx >> 4, ch = idx & 15;           // 16 chunks of 8 per row
        const float* wp = W + (size_t)row * FF + ch * 8;
        float4 v0 = *(const float4*)wp;
        float4 v1 = *(const float4*)(wp + 4);
        unsigned int u[4];
        u[0] = pack2_rtne(v0.x, v0.y); u[1] = pack2_rtne(v0.z, v0.w);
        u[2] = pack2_rtne(v1.x, v1.y); u[3] = pack2_rtne(v1.z, v1.w);
        *(int4*)&wbf[row][ch * 8] = *(const int4*)u;
    }
    __syncthreads();

    // per-head column sums: vs[h][i] = sum_d W[h*32+d][i]*a_src[h][d]
    {
        int i = t & 127;
        float acc4[4] = {0.f, 0.f, 0.f, 0.f};
        if (t < 128) {
            for (int o = 0; o < 128; ++o) {
                float wv = __uint_as_float(((unsigned int)wbf[o][i]) << 16);
                acc4[o >> 5] += wv * as_s[o];
            }
#pragma unroll
            for (int hd = 0; hd < 4; ++hd) vs_s[hd][i] = acc4[hd];
        } else {
            for (int o = 0; o < 128; ++o) {
                float wv = __uint_as_float(((unsigned int)wbf[o][i]) << 16);
                acc4[o >> 5] += wv * ad_s[o];
            }
#pragma unroll
            for (int hd = 0; hd < 4; ++hd) vd_s[hd][i] = acc4[hd];
        }
    }

    // MFMA: h[m0g..+15][0..127] ; wave wid does col-tiles c=wid*2, wid*2+1
    int wid = t >> 6, lane = t & 63;
    int r = lane & 15, q = lane >> 4;
    floatx4 acc[2] = {{0.f,0.f,0.f,0.f},{0.f,0.f,0.f,0.f}};
    const float* xrow = x + (size_t)(m0g + r) * FF + q * 8;
#pragma unroll
    for (int kk = 0; kk < 4; ++kk) {
        float4 a0 = *(const float4*)(xrow + kk * 32);
        float4 a1 = *(const float4*)(xrow + kk * 32 + 4);
        union { short8 s8; unsigned int u[4]; } af;
        af.u[0] = pack2_rtne(a0.x, a0.y); af.u[1] = pack2_rtne(a0.z, a0.w);
        af.u[2] = pack2_rtne(a1.x, a1.y); af.u[3] = pack2_rtne(a1.z, a1.w);
#pragma unroll
        for (int c = 0; c < 2; ++c) {
            int o = (wid * 2 + c) * 16 + r;          // B col = lane&15
            short8 bf = *(const short8*)&wbf[o][kk * 32 + q * 8];
            acc[c] = __builtin_amdgcn_mfma_f32_16x16x32_bf16(af.s8, bf, acc[c], 0, 0, 0);
        }
    }
    // store h^T (bf16) to LDS: lane holds col o, rows q*4+reg
#pragma unroll
    for (int c = 0; c < 2; ++c) {
        int o = (wid * 2 + c) * 16 + r;
        unsigned int u2[2];
        u2[0] = pack2_rtne(acc[c][0], acc[c][1]);
        u2[1] = pack2_rtne(acc[c][2], acc[c][3]);
        *(int2*)&hbf[o][q * 4] = *(const int2*)u2;
    }
    __syncthreads();

    // ht write: thread t<128 handles col o=t -> ht[b*4+hd][d][m_block..+15]
    if (t < 128) {
        int hd = t >> 5, d = t & 31;
        unsigned short* op = ht + ((size_t)(b * HH + hd) * DD + d) * NN + m_block;
        *(int4*)op       = *(const int4*)&hbf[t][0];
        *(int4*)(op + 8) = *(const int4*)&hbf[t][8];
    }
    // es/ed in fp32: thread (m = t>>4, sg = t&15), partial over i = sg*8..+7
    {
        int m = t >> 4, sg = t & 15;
        const float* xp = x + (size_t)(m0g + m) * FF + sg * 8;
        float4 x0 = *(const float4*)xp;
        float4 x1 = *(const float4*)(xp + 4);
#pragma unroll
        for (int hd = 0; hd < 4; ++hd) {
            const float* vsp = &vs_s[hd][sg * 8];
            const float* vdp = &vd_s[hd][sg * 8];
            float es = x0.x * vsp[0] + x0.y * vsp[1] + x0.z * vsp[2] + x0.w * vsp[3]
                     + x1.x * vsp[4] + x1.y * vsp[5] + x1.z * vsp[6] + x1.w * vsp[7];
            float ed = x0.x * vdp[0] + x0.y * vdp[1] + x0.z * vdp[2] + x0.w * vdp[3]
                     + x1.x * vdp[4] + x1.y * vdp[5] + x1.z * vdp[6] + x1.w * vdp[7];
#pragma unroll
            for (int k = 1; k < 16; k <<= 1) {
                es += __shfl_xor(es, k);
                ed += __shfl_xor(ed, k);
            }
            if (sg == 0) {
                size_t eb = (size_t)(b * HH + hd) * NN + m_block + m;
                es_t[eb] = es * LOG2E;
                ed_t[eb] = ed * LOG2E;
            }
        }
    }
}

// ---------------- K2: fused masked-softmax attention + PV via MFMA (R5 VERBATIM)
// grid (16,16), 1024 thr (16 waves, K-split halves), 1 block/CU, 144.5KB LDS.
#define HTS 2056
__global__ __launch_bounds__(1024) void k_attn(
        const unsigned short* __restrict__ ht,
        const unsigned int* __restrict__ bits,
        const float* __restrict__ es_t,
        const float* __restrict__ ed_t,
        float* __restrict__ out) {
    __shared__ unsigned short hb[DD * HTS];   // 128.5 KB
    __shared__ float ep[NN * 2];               // 16 KB: (Ed_p, Ed_n) per m
    int t = threadIdx.x;
    int n0 = blockIdx.x * 128;
    int bh = blockIdx.y;
    int b = bh >> 2, head = bh & 3;

    int wid = t >> 6, lane = t & 63;
    int q = lane >> 4, r = lane & 15;
    int qo = q * 8;
    int half = wid >> 3, wsub = wid & 7;
    int n_l = wsub * 16 + r;

    // stage (Ed_p, Ed_n) pairs: 2 m per thread
    {
        float2 v = ((const float2*)(ed_t + (size_t)bh * NN))[t];
        float4 o;
        o.x = exp2_fast(v.x); o.y = exp2_fast(NEG_SLOPE * v.x);
        o.z = exp2_fast(v.y); o.w = exp2_fast(NEG_SLOPE * v.y);
        ((float4*)ep)[t] = o;
    }
    // stage full ht slice: 8192 int4 chunks
    {
        const unsigned short* htp = ht + (size_t)bh * DD * NN;
#pragma unroll
        for (int k = 0; k < 8; ++k) {
            int qq = t + k * 1024;
            int d = qq >> 8, cm = qq & 255;
            int4 v = *(const int4*)(htp + (size_t)d * NN + cm * 8);
            *(int4*)&hb[d * HTS + cm * 8] = v;
        }
    }
    // adjacency bits for this lane's row + K-half: 32 words in registers
    int4 bw[8];
    {
        const int4* bp = (const int4*)(bits + (size_t)(n0 + n_l) * 64 + half * 32);
#pragma unroll
        for (int g = 0; g < 8; ++g) bw[g] = bp[g];
    }
    float esv = es_t[(size_t)bh * NN + n0 + n_l];
    floatx2 es2 = {exp2_fast(esv), exp2_fast(NEG_SLOPE * esv)};
    __syncthreads();

    floatx4 acc0 = {0.f, 0.f, 0.f, 0.f};
    floatx4 acc1 = {0.f, 0.f, 0.f, 0.f};
    floatx4 accd = {0.f, 0.f, 0.f, 0.f};
    union { short8 s8; int i[4]; } ones;
    ones.i[0] = 0x3F803F80; ones.i[1] = 0x3F803F80;
    ones.i[2] = 0x3F803F80; ones.i[3] = 0x3F803F80;

    const float* eph = ep + half * 2048;
    const unsigned short* hrow0 = &hb[r * HTS + half * 1024 + qo];
    const unsigned short* hrow1 = hrow0 + 16 * HTS;

#pragma unroll
    for (int g = 0; g < 8; ++g) {
#pragma unroll
        for (int c = 0; c < 4; ++c) {
            unsigned int word = (unsigned int)((&bw[g].x)[c]);
            int mb = (g * 4 + c) * 32;
            unsigned int wq = word >> qo;
            const float* pbase = eph + (mb + qo) * 2;
            union { short8 s8; int i[4]; } af;
#pragma unroll
            for (int jp = 0; jp < 4; ++jp) {
                float4 d2 = *(const float4*)(pbase + jp * 4);
                floatx2 p0 = es2 * (floatx2){d2.x, d2.y};
                floatx2 p1 = es2 * (floatx2){d2.z, d2.w};
                float w0 = fmaxf(p0.x, p0.y);
                float w1 = fmaxf(p1.x, p1.y);
                int m0 = bit_mask(wq, 2 * jp);
                int m1 = bit_mask(wq, 2 * jp + 1);
                w0 = __uint_as_float(__float_as_uint(w0) & (unsigned int)m0);
                w1 = __uint_as_float(__float_as_uint(w1) & (unsigned int)m1);
                af.i[jp] = __builtin_amdgcn_perm(__float_as_uint(w1),
                                                 __float_as_uint(w0),
                                                 0x07060302u);
            }
            short8 b0 = *(const short8*)(hrow0 + mb);
            short8 b1 = *(const short8*)(hrow1 + mb);
            acc0 = __builtin_amdgcn_mfma_f32_16x16x32_bf16(af.s8, b0, acc0, 0, 0, 0);
            acc1 = __builtin_amdgcn_mfma_f32_16x16x32_bf16(af.s8, b1, acc1, 0, 0, 0);
            accd = __builtin_amdgcn_mfma_f32_16x16x32_bf16(af.s8, ones.s8, accd, 0, 0, 0);
        }
    }

    // K-half pair reduction through LDS (reuse hb as fp32 scratch)
    __syncthreads();
    float* scr = (float*)hb;
    if (wid >= 8) {
        int base = ((wid - 8) * 64 + lane) * 12;
        *(floatx4*)&scr[base + 0] = acc0;
        *(floatx4*)&scr[base + 4] = acc1;
        *(floatx4*)&scr[base + 8] = accd;
    }
    __syncthreads();
    if (wid < 8) {
        int base = (wid * 64 + lane) * 12;
        floatx4 p0 = *(const floatx4*)&scr[base + 0];
        floatx4 p1 = *(const floatx4*)&scr[base + 4];
        floatx4 pd = *(const floatx4*)&scr[base + 8];
#pragma unroll
        for (int k = 0; k < 4; ++k) {
            acc0[k] += p0[k]; acc1[k] += p1[k]; accd[k] += pd[k];
        }
        // C/D layout: col = lane&15 (= r), row = q*4 + reg
#pragma unroll
        for (int reg = 0; reg < 4; ++reg) {
            int nrow = n0 + wsub * 16 + q * 4 + reg;
            float inv = 1.0f / accd[reg];
            float* op = out + ((size_t)(b * NN + nrow)) * FF + head * DD;
            op[r]      = acc0[reg] * inv;
            op[16 + r] = acc1[reg] * inv;
        }
    }
}

extern "C" void kernel_launch(void* const* d_in, const int* in_sizes, int n_in,
                              void* d_out, int out_size, void* d_ws, size_t ws_size,
                              hipStream_t stream) {
    const float* x     = (const float*)d_in[0];
    const int*   adj   = (const int*)d_in[1];
    const float* W     = (const float*)d_in[2];
    const float* a_src = (const float*)d_in[3];
    const float* a_dst = (const float*)d_in[4];
    float* out = (float*)d_out;

    float* es_t = (float*)d_ws;                                // 32,768 f
    float* ed_t = es_t + (size_t)BB * HH * NN;                 // 32,768 f
    unsigned int* bits = (unsigned int*)(ed_t + (size_t)BB * HH * NN);     // 131,072 u32
    unsigned short* ht = (unsigned short*)(bits + (size_t)NN * (NN / 32)); // 2,097,152 bf16

    hipLaunchKernelGGL(k_prep, dim3(1024), dim3(256), 0, stream,
                       x, W, a_src, a_dst, adj, ht, es_t, ed_t, bits);
    hipLaunchKernelGGL(k_attn, dim3(NN / 128, BB * HH), dim3(1024), 0, stream,
                       ht, bits, es_t, ed_t, out);
}